// Round 1
// baseline (2341.859 us; speedup 1.0000x reference)
//
#include <hip/hip_runtime.h>
#include <hip/hip_fp16.h>
#include <math.h>

// ---- geometry ----
#define VIEWS  360
#define NDET   512
#define CH     8
#define RR     11                    // interpolation taps (2*range_x+1)
#define HID    176                   // fc1 out channels
#define OC     88                    // fc2 out channels = RR*CH
#define LPOS   (VIEWS*NDET*RR)       // 2,027,520 positions
#define NIDX   (128*128*VIEWS)       // 5,898,240 indices
#define DCHUNK 64
#define NCHUNK (NDET/DCHUNK)

// ws layout: fp16, [pos][16] with bc = b*8 + c  -> one 32B chunk per position.
// Needs LPOS*16*2 = 64.9 MB of d_ws.

// ---------------- Kernel A: per-(b,v) Conv1d->GELU->Conv1d into ws ----------------
__global__ __launch_bounds__(256) void mlp_kernel(
    const float* __restrict__ input,   // [2, 8, 360, 512]
    const float* __restrict__ w1,      // [176, 8, 3]
    const float* __restrict__ b1,      // [176]
    const float* __restrict__ w2,      // [88, 176, 3]
    const float* __restrict__ b2,      // [88]
    __half* __restrict__ ws)
{
    const int v   = blockIdx.x;
    const int b   = blockIdx.y;
    const int tid = threadIdx.x;

    __shared__ float x_s[CH * 514];     // x_s[c][d+1], d=-1..512, zero edges
    __shared__ float h_s[HID * 66];     // h_s[o][dd], dd=0..65 <-> d = d0-1+dd

    // stage x into LDS (coalesced), zero-pad both ends
    for (int j = tid; j < CH * NDET; j += 256) {
        int c = j >> 9, d = j & 511;
        x_s[c * 514 + d + 1] = input[((b * CH + c) * VIEWS + v) * NDET + d];
    }
    if (tid < CH * 2) {
        int c = tid >> 1;
        x_s[c * 514 + ((tid & 1) ? 513 : 0)] = 0.f;
    }
    __syncthreads();

    const int lane = tid & 63;
    const int o2g  = tid >> 6;    // 0..3, wave-uniform
    // force SGPR base for w2 rows (wave-uniform) -> s_load weight reads
    const int obase = __builtin_amdgcn_readfirstlane(o2g * 22 * (HID * 3));

    for (int chunk = 0; chunk < NCHUNK; ++chunk) {
        const int d0 = chunk * DCHUNK;

        // ---- conv1 + exact GELU into h_s (halo dd=0 and dd=65; zero outside [0,512)) ----
        for (int i = tid; i < HID * 66; i += 256) {
            int o  = i / 66;
            int dd = i - o * 66;
            int d  = d0 - 1 + dd;
            float val = 0.f;
            if (d >= 0 && d < NDET) {
                float acc = b1[o];
                const float* wr = w1 + o * 24;
                #pragma unroll
                for (int c = 0; c < CH; ++c) {
                    const float* xs = x_s + c * 514 + d;   // xs[k] = x[d+k-1]
                    acc += wr[c * 3 + 0] * xs[0]
                         + wr[c * 3 + 1] * xs[1]
                         + wr[c * 3 + 2] * xs[2];
                }
                val = 0.5f * acc * (1.0f + erff(acc * 0.70710678118654752f));
            }
            h_s[i] = val;   // i == o*66 + dd
        }
        __syncthreads();

        // ---- conv2: thread computes 22 o2 values at d = d0 + lane ----
        float acc[22];
        #pragma unroll
        for (int j = 0; j < 22; ++j) acc[j] = b2[o2g * 22 + j];

        for (int hh = 0; hh < HID; ++hh) {
            float h0 = h_s[hh * 66 + lane + 0];
            float h1 = h_s[hh * 66 + lane + 1];
            float h2 = h_s[hh * 66 + lane + 2];
            const float* w2r = w2 + obase + hh * 3;
            #pragma unroll
            for (int j = 0; j < 22; ++j) {
                acc[j] += w2r[j * 528 + 0] * h0
                        + w2r[j * 528 + 1] * h1
                        + w2r[j * 528 + 2] * h2;
            }
        }

        // ---- store to ws[pos][16] as fp16 ----
        const int d = d0 + lane;
        #pragma unroll
        for (int j = 0; j < 22; ++j) {
            int o2 = o2g * 22 + j;
            int c  = o2 / 11;
            int r  = o2 - c * 11;
            int pos = (v * NDET + d) * RR + r;
            ws[pos * 16 + b * 8 + c] = __float2half(acc[j]);
        }
        __syncthreads();
    }
}

// ---------------- Kernel B: interpolation gather ----------------
__global__ __launch_bounds__(256) void gather_kernel(
    const float* __restrict__ indices,
    const __half* __restrict__ ws,
    float* __restrict__ out)
{
    int i = blockIdx.x * 256 + threadIdx.x;
    if (i >= NIDX) return;

    float idx      = indices[i];
    float idx_low  = floorf(idx);
    float w        = idx - idx_low;
    float fw       = floorf(w * 5.0f);
    float low_ind  = idx_low * 11.0f + 5.0f + fw;
    float low_w    = w * 5.0f - fw;
    float high_ind = low_ind + 6.0f;
    if (high_ind >= (float)(LPOS - 1)) high_ind = (float)(LPOS - 2);
    int li = (int)low_ind;
    int hi = (int)high_ind;

    const uint4* wsv = (const uint4*)ws;   // 8 halves per uint4; 2 per position
    float omlw = 1.0f - low_w;
    float omw  = 1.0f - w;

    #pragma unroll
    for (int part = 0; part < 2; ++part) {
        uint4 A  = wsv[(size_t)li * 2 + part];
        uint4 Bv = wsv[(size_t)(li + 1) * 2 + part];
        uint4 Cv = wsv[(size_t)hi * 2 + part];
        uint4 Dv = wsv[(size_t)(hi + 1) * 2 + part];
        const __half* ah = (const __half*)&A;
        const __half* bh = (const __half*)&Bv;
        const __half* ch = (const __half*)&Cv;
        const __half* dh = (const __half*)&Dv;
        #pragma unroll
        for (int j = 0; j < 8; ++j) {
            float a  = __half2float(ah[j]);
            float bb = __half2float(bh[j]);
            float cc = __half2float(ch[j]);
            float dd = __half2float(dh[j]);
            float lo = a  * omlw + bb * low_w;
            float hv = cc * omlw + dd * low_w;
            float r  = lo * omw + hv * w;
            out[(size_t)(part * 8 + j) * NIDX + i] = r;
        }
    }
}

extern "C" void kernel_launch(void* const* d_in, const int* in_sizes, int n_in,
                              void* d_out, int out_size, void* d_ws, size_t ws_size,
                              hipStream_t stream) {
    const float* input   = (const float*)d_in[0];
    const float* indices = (const float*)d_in[1];
    const float* w1      = (const float*)d_in[2];
    const float* b1      = (const float*)d_in[3];
    const float* w2      = (const float*)d_in[4];
    const float* b2      = (const float*)d_in[5];
    __half* ws = (__half*)d_ws;
    float* out = (float*)d_out;

    dim3 gridA(VIEWS, 2);
    mlp_kernel<<<gridA, 256, 0, stream>>>(input, w1, b1, w2, b2, ws);

    int nb = (NIDX + 255) / 256;
    gather_kernel<<<nb, 256, 0, stream>>>(indices, ws, out);
}